// Round 5
// baseline (898.635 us; speedup 1.0000x reference)
//
#include <hip/hip_runtime.h>
#include <cstdint>
#include <cstddef>

// Problem constants (match reference config)
#define TT   4096     // tokens
#define HH   1024     // hidden
#define II   512      // moe intermediate
#define EE   64       // experts
#define KT   8        // top-k
#define ISZ  1024     // shared intermediate (I*NSH)
#define TKA  32768    // T*K assignments
#define TKAP (TKA + 2048)  // padded slots (16-align per expert + last-tile overhang)
#define MAXT 320      // max M-tiles: sum ceil(n_e/128) <= 256+64

typedef __bf16 bf16x8 __attribute__((ext_vector_type(8)));
typedef float  f32x4  __attribute__((ext_vector_type(4)));
typedef unsigned short us8v __attribute__((ext_vector_type(8)));

__device__ __forceinline__ unsigned short f2bf(float f) {
  unsigned u = __float_as_uint(f);
  u += 0x7fffu + ((u >> 16) & 1u);   // RNE (finite inputs only)
  return (unsigned short)(u >> 16);
}

// async global->LDS, 16B/lane; LDS dest is wave-uniform base + lane*16
#define GLDS(gp, lp) __builtin_amdgcn_global_load_lds( \
    (const __attribute__((address_space(1))) void*)(gp), \
    (__attribute__((address_space(3))) void*)(lp), 16, 0, 0)

// PACKED weight layout: logical [N][K] bf16 stored as subtiles of 16n x 32k
// (1024 B contiguous). Element (n&15, k) sits at (n&15)*32 + s*8 + (k&7),
// s = ((k>>3)&3 + ((n>>1)&3)) & 3. Key property: an MFMA B-fragment read of
// one subtile is lane-contiguous (lane cl,quad reads shorts cl*32+sw8..+7),
// so fragments load DIRECTLY global->VGPR as one coalesced dwordx4 per lane,
// no LDS round-trip. B never touches LDS; only A is staged (halves the
// LDS-pipe load that bounded the old kernel).

// ---------------- transpose + fp32->bf16 + PACK: in[b][R][C] -> packed [C][R]
// (R = K dim, C = N dim). Writes ushort8 (16 B/lane), one subtile slot each.
__global__ __launch_bounds__(256) void k_transpose(const float* __restrict__ in,
                                                   unsigned short* __restrict__ out,
                                                   int R, int C) {
  __shared__ float tile[64][65];
  long b = blockIdx.z;
  int r0 = blockIdx.x * 64, c0 = blockIdx.y * 64;
  const float* ip = in + b * (long)R * C;
  unsigned short* op = out + b * (long)R * C;
  int tc = threadIdx.x & 63, tr = threadIdx.x >> 6;
#pragma unroll
  for (int rr = 0; rr < 64; rr += 4)
    tile[tr + rr][tc] = ip[(long)(r0 + tr + rr) * C + (c0 + tc)];
  __syncthreads();
  int kt = R >> 5;   // k-tiles per n-group
#pragma unroll
  for (int p = 0; p < 2; p++) {
    int sid = p * 256 + threadIdx.x;     // 512 slots: 64 n x 8 kq
    int nl = sid >> 3, kq = sid & 7;
    int n = c0 + nl;
    int kg = r0 + kq * 8;
    int s = ((kq & 3) + ((n >> 1) & 3)) & 3;
    long off = ((long)(n >> 4) * kt + (kg >> 5)) * 512 + (n & 15) * 32 + s * 8;
    us8v v;
#pragma unroll
    for (int j = 0; j < 8; j++) v[j] = f2bf(tile[kq * 8 + j][nl]);
    *(us8v*)(op + off) = v;
  }
}

// ---------------- fp32 -> bf16 elementwise (x, row-major; A-gather source)
__global__ __launch_bounds__(256) void k_cvt(const float* __restrict__ in,
                                             unsigned short* __restrict__ out) {
  int i = blockIdx.x * 256 + threadIdx.x;
  float4 v = ((const float4*)in)[i];
  ushort4 o;
  o.x = f2bf(v.x); o.y = f2bf(v.y); o.z = f2bf(v.z); o.w = f2bf(v.w);
  ((ushort4*)out)[i] = o;
}

// ---------------- router: fp64-accurate logits -> sigmoid -> wave-parallel
// grouped top-k (lane = expert, all state in registers, shuffles only).
__global__ __launch_bounds__(256) void k_router(const float* __restrict__ x,
    const float* __restrict__ gw, const float* __restrict__ eb,
    int* __restrict__ topk_ids, float* __restrict__ topk_w, int* __restrict__ counts)
{
  __shared__ float xrow[HH];
  __shared__ float sc[EE];
  int t = blockIdx.x;
  int tid = threadIdx.x;
  for (int i = tid; i < HH; i += 256) xrow[i] = x[(long)t * HH + i];
  __syncthreads();
  int e = tid >> 2, q = tid & 3;          // 4 threads per expert
  const float* w = gw + (long)e * HH;
  double acc = 0.0, acc2 = 0.0;           // 2 chains to halve dep latency
  for (int i = q * 8; i < HH; i += 32) {
    float4 wa = *(const float4*)(w + i);
    float4 wb = *(const float4*)(w + i + 4);
    acc  += (double)wa.x * (double)xrow[i]
          + (double)wa.y * (double)xrow[i + 1]
          + (double)wa.z * (double)xrow[i + 2]
          + (double)wa.w * (double)xrow[i + 3];
    acc2 += (double)wb.x * (double)xrow[i + 4]
          + (double)wb.y * (double)xrow[i + 5]
          + (double)wb.z * (double)xrow[i + 6]
          + (double)wb.w * (double)xrow[i + 7];
  }
  acc += acc2;
  acc += __shfl_down(acc, 2);
  acc += __shfl_down(acc, 1);
  if (q == 0) sc[e] = (float)(1.0 / (1.0 + exp(-acc)));
  __syncthreads();
  if (tid < 64) {                          // wave 0, lane = expert
    int lane = tid;
    float s = sc[lane];
    float sfc = s + eb[lane];
    // --- top-2 within each group of 8 lanes (butterfly top-2 merge)
    float m1 = sfc, m2 = -1e30f;
#pragma unroll
    for (int d = 1; d < 8; d <<= 1) {
      float o1 = __shfl_xor(m1, d);
      float o2 = __shfl_xor(m2, d);
      float hi = fmaxf(m1, o1);
      float lo = fminf(m1, o1);
      m2 = fmaxf(lo, fmaxf(m2, o2));
      m1 = hi;
    }
    float gs = m1 + m2;                    // group score (uniform within group)
    int g = lane >> 3;
    // --- rank my group among 8 (ties -> lowest group idx), select top-4
    int grank = 0;
#pragma unroll
    for (int j = 0; j < 8; j++) {
      float gj = __shfl(gs, j * 8);
      if (gj > gs || (gj == gs && j < g)) grank++;
    }
    bool gsel = grank < 4;
    float mv = gsel ? sfc : 0.0f;          // masked_fill(~mask, 0.0) as in ref
    // --- rank among all 64 (ties -> lowest lane), select top-8
    int rank = 0;
    for (int j = 0; j < 64; j++) {
      float vj = __shfl(mv, j);
      if (vj > mv || (vj == mv && j < lane)) rank++;
    }
    bool sel = rank < KT;
    float ssum = sel ? s : 0.0f;           // renorm sum of RAW scores
#pragma unroll
    for (int d = 1; d < 64; d <<= 1) ssum += __shfl_xor(ssum, d);
    unsigned long long bal = __ballot(sel);
    if (sel) {
      int pos = __popcll(bal & ((1ull << lane) - 1ull));
      topk_ids[(long)t * KT + pos] = lane;
      topk_w[(long)t * KT + pos] = s / ssum;
      atomicAdd(&counts[lane], 1);
    }
  }
}

// ---------------- offsets (16-aligned per expert) + static tile table
// + zero-init of padding slots in perm/wslot (they get staged but masked).
__global__ void k_offsets(const int* __restrict__ counts, int* __restrict__ offsets,
                          int* __restrict__ cursor, int* __restrict__ tile_e,
                          int* __restrict__ tile_r0, int* __restrict__ perm,
                          float* __restrict__ wslot)
{
  int lane = threadIdx.x;                  // 64 threads = 1 wave
  int c = counts[lane];
  int ca = (c + 15) & ~15;                 // 16-aligned (packed-subtile alignment)
  int xs = ca;                             // inclusive prefix sum of padded counts
#pragma unroll
  for (int d = 1; d < 64; d <<= 1) { int y = __shfl_up(xs, d); if (lane >= d) xs += y; }
  int off = xs - ca;                       // exclusive (16-aligned)
  offsets[lane] = off;
  cursor[lane] = off;
  if (lane == 63) offsets[EE] = xs;
  int nt = (c + 127) >> 7;                 // M-tiles for this expert
  int tp = nt;                             // inclusive prefix sum of tiles
#pragma unroll
  for (int d = 1; d < 64; d <<= 1) { int y = __shfl_up(tp, d); if (lane >= d) tp += y; }
  int tbase = tp - nt;
  for (int i = 0; i < nt; i++) { tile_e[tbase + i] = lane; tile_r0[tbase + i] = off + i * 128; }
  int total = __shfl(tp, 63);
  for (int i = total + lane; i < MAXT; i += 64) tile_e[i] = -1;
  // zero padding slots [off+c, off+ca) so staged perm/wslot are defined
  for (int i = off + c; i < off + ca; i++) { perm[i] = 0; wslot[i] = 0.f; }
  // last expert's tile overhang [paddedTotal, lastTileEnd)
  int ptotal = __shfl(xs, 63);
  int lastEnd = __shfl(off + nt * 128, 63);
  for (int i = ptotal + lane; i < lastEnd; i += 64) { perm[i] = 0; wslot[i] = 0.f; }
}

// ---------------- scatter assignments into expert-sorted slot order
__global__ __launch_bounds__(256) void k_scatter(const int* __restrict__ ids,
    const float* __restrict__ tw, int* __restrict__ cursor,
    int* __restrict__ perm, float* __restrict__ wslot, int* __restrict__ inv)
{
  int a = blockIdx.x * 256 + threadIdx.x;
  int e = ids[a];
  int pos = atomicAdd(&cursor[e], 1);
  perm[pos] = a >> 3;     // token index
  wslot[pos] = tw[a];
  inv[a] = pos;           // token t, k-th pick -> slot
}

// ---------------- GEMM1 (gate_up) + fused silu*mul. Twin accumulators:
// block: 128 rows x 64 gate cols + 64 up cols. 4 waves (2x2), 16x16x32 bf16 MFMA.
// A: 3-deep LDS ring (8 KB/slot), counted vmcnt. B: DIRECT global->VGPR
// fragment loads from packed layout, register-prefetched one K-step ahead
// (L2-resident via XCD-chunked tile order). Epilogue writes Hout PACKED.
__global__ __launch_bounds__(256, 4) void k_gemm_gu(
    const unsigned short* __restrict__ Abase, const int* __restrict__ perm,
    const unsigned short* __restrict__ Bbase, long eStride, int Kd, int upOff,
    unsigned short* __restrict__ Hout,
    const int* __restrict__ tile_e, const int* __restrict__ tile_r0,
    const int* __restrict__ eoff, int rowsTotal)
{
  __shared__ __align__(16) unsigned short lds[12288];  // 3 x A(4096 shorts)
  // XCD swizzle: D%8 = XCD; each XCD owns gridDim.x/8 contiguous M-tiles, N-fastest
  int D = blockIdx.y * gridDim.x + blockIdx.x;
  int cx = D & 7, jj = D >> 3;
  int chunk = gridDim.x >> 3;
  int mt = cx * chunk + jj / gridDim.y;
  int ny = jj - (jj / gridDim.y) * gridDim.y;
  int e = 0, row0, end;
  if (tile_e) {
    e = tile_e[mt];
    if (e < 0) return;
    row0 = tile_r0[mt];
    end = eoff[e + 1];
  } else { row0 = mt * 128; end = rowsTotal; }
  int n0 = ny * 64;
  int tid = threadIdx.x, lane = tid & 63, wave = tid >> 6;
  int wm = wave >> 1, wn = wave & 1;
  int lr = lane >> 2;
  int lkq = ((((lane & 3) - ((lane >> 3) & 3)) & 3)) * 8;  // swizzled k-chunk (A path)
  int r0a = row0 + wave * 32 + lr;
  int r1a = r0a + 16;
  int t0 = r0a < rowsTotal ? r0a : rowsTotal - 1;
  int t1 = r1a < rowsTotal ? r1a : rowsTotal - 1;
  if (perm) { t0 = perm[t0]; t1 = perm[t1]; }
  const unsigned short* ap0 = Abase + (long)t0 * Kd + lkq;
  const unsigned short* ap1 = Abase + (long)t1 * Kd + lkq;
  int nkt = Kd >> 5;                       // packed k-tiles per n-group
  int quad = lane >> 4, cl = lane & 15;
  int sw8 = ((quad + ((cl >> 1) & 3)) & 3) * 8;   // swizzled read slot
  long fragoff = (long)cl * 32 + sw8;             // lane's 16B within a subtile
  long ebase = (long)e * eStride;
  const unsigned short* Bg0 = Bbase + ebase + ((long)((n0 >> 4) + wn * 2)     * nkt) * 512 + fragoff;
  const unsigned short* Bg1 = Bbase + ebase + ((long)((n0 >> 4) + wn * 2 + 1) * nkt) * 512 + fragoff;
  const unsigned short* Bu0 = Bbase + ebase + ((long)(((upOff + n0) >> 4) + wn * 2)     * nkt) * 512 + fragoff;
  const unsigned short* Bu1 = Bbase + ebase + ((long)(((upOff + n0) >> 4) + wn * 2 + 1) * nkt) * 512 + fragoff;
  unsigned short* lA0 = lds + wave * 1024 + lane * 8;   // rows wave*32.. (+512 = +16 rows)
  f32x4 acc[4][4];
  f32x4 z = {0.f, 0.f, 0.f, 0.f};
  for (int i = 0; i < 4; i++) for (int j = 0; j < 4; j++) acc[i][j] = z;
  int nk = Kd >> 5;                               // >= 16 always
  // prologue: stage A tiles 0,1 into ring slots 0,1; then load B(0) to regs
  GLDS(ap0, lA0);             GLDS(ap1, lA0 + 512);
  GLDS(ap0 + 32, lA0 + 4096); GLDS(ap1 + 32, lA0 + 4096 + 512);
  asm volatile("" ::: "memory");    // pin: GLDS issue before B loads (vmcnt FIFO)
  bf16x8 cg0 = *(const bf16x8*)(Bg0);
  bf16x8 cg1 = *(const bf16x8*)(Bg1);
  bf16x8 cu0 = *(const bf16x8*)(Bu0);
  bf16x8 cu1 = *(const bf16x8*)(Bu1);
  int cur = 0, nxt = 4096, fut = 8192;
  for (int t = 0; t < nk; ++t) {
    __builtin_amdgcn_s_barrier();          // A: all waves done reading ring[fut]
    if (t + 2 < nk) {
      int k2 = (t + 2) << 5;
      GLDS(ap0 + k2, lA0 + fut); GLDS(ap1 + k2, lA0 + fut + 512);
      asm volatile("s_waitcnt vmcnt(8)" ::: "memory");   // A(t) landed (FIFO)
    } else if (t + 1 < nk) {
      asm volatile("s_waitcnt vmcnt(6)" ::: "memory");
    } else {
      asm volatile("s_waitcnt vmcnt(4)" ::: "memory");
    }
    __builtin_amdgcn_s_barrier();          // B: tile t visible to all waves
    asm volatile("" ::: "memory");         // pin ds_reads/loads below barrier B
    // register-prefetch B fragments for step t+1 (independent of this step)
    bf16x8 ng0, ng1, nu0, nu1;
    if (t + 1 < nk) {
      long o = (long)(t + 1) * 512;
      ng0 = *(const bf16x8*)(Bg0 + o);
      ng1 = *(const bf16x8*)(Bg1 + o);
      nu0 = *(const bf16x8*)(Bu0 + o);
      nu1 = *(const bf16x8*)(Bu1 + o);
    }
    bf16x8 af[4];
#pragma unroll
    for (int mi = 0; mi < 4; mi++)
      af[mi] = *(const bf16x8*)(lds + cur + (wm * 64 + mi * 16 + cl) * 32 + sw8);
#pragma unroll
    for (int mi = 0; mi < 4; mi++) {
      acc[mi][0] = __builtin_amdgcn_mfma_f32_16x16x32_bf16(af[mi], cg0, acc[mi][0], 0, 0, 0);
      acc[mi][1] = __builtin_amdgcn_mfma_f32_16x16x32_bf16(af[mi], cg1, acc[mi][1], 0, 0, 0);
      acc[mi][2] = __builtin_amdgcn_mfma_f32_16x16x32_bf16(af[mi], cu0, acc[mi][2], 0, 0, 0);
      acc[mi][3] = __builtin_amdgcn_mfma_f32_16x16x32_bf16(af[mi], cu1, acc[mi][3], 0, 0, 0);
    }
    asm volatile("" ::: "memory");         // pin ds_reads above next barrier A
    if (t + 1 < nk) { cg0 = ng0; cg1 = ng1; cu0 = nu0; cu1 = nu1; }
    int tmp = cur; cur = nxt; nxt = fut; fut = tmp;
  }
  int ntO = upOff >> 5;                    // packed k-tiles of output (K = upOff)
#pragma unroll
  for (int mi = 0; mi < 4; mi++) {
#pragma unroll
    for (int j = 0; j < 2; j++) {
#pragma unroll
      for (int r = 0; r < 4; r++) {
        int row = row0 + wm * 64 + mi * 16 + quad * 4 + r;
        if (row < end) {
          float g = acc[mi][j][r], u = acc[mi][j + 2][r];
          float hv = g * (1.f / (1.f + __expf(-g))) * u;   // silu(g)*u
          int col = n0 + wn * 32 + j * 16 + cl;
          int sl = (((col >> 3) & 3) + ((row >> 1) & 3)) & 3;
          long offp = ((long)(row >> 4) * ntO + (col >> 5)) * 512
                    + (row & 15) * 32 + sl * 8 + (col & 7);
          Hout[offp] = f2bf(hv);
        }
      }
    }
  }
}

// ---------------- GEMM2 (down). 128x128 tile. A: 3-deep LDS ring (packed hb,
// coalesced GLDS). B: direct global->VGPR packed fragments, reg-prefetched.
// mode 0: plain fp32 store to Out (shared path)
// mode 1: scaled bf16 store to Out (routed ys; scale = wslot*2.5)
__global__ __launch_bounds__(256, 4) void k_gemm_down(
    const unsigned short* __restrict__ Abase,
    const unsigned short* __restrict__ Bbase, long eStride, int Kd,
    void* __restrict__ Outv, const float* __restrict__ wslot,
    const int* __restrict__ tile_e, const int* __restrict__ tile_r0,
    const int* __restrict__ eoff, int rowsTotal, int mode)
{
  __shared__ __align__(16) unsigned short lds[12288];  // 3 x A(4096 shorts)
  int D = blockIdx.y * gridDim.x + blockIdx.x;
  int cx = D & 7, jj = D >> 3;
  int chunk = gridDim.x >> 3;
  int mt = cx * chunk + jj / gridDim.y;
  int ny = jj - (jj / gridDim.y) * gridDim.y;
  int e = 0, row0, end;
  if (tile_e) {
    e = tile_e[mt];
    if (e < 0) return;
    row0 = tile_r0[mt];                    // 16-aligned (padded offsets)
    end = eoff[e + 1];
  } else { row0 = mt * 128; end = rowsTotal; }
  int n0 = ny * 128;
  int tid = threadIdx.x, lane = tid & 63, wave = tid >> 6;
  int wm = wave >> 1, wn = wave & 1;
  int nkt = Kd >> 5;
  long sstep = (long)nkt * 512;            // next n-group subtile stride
  const unsigned short* apk = Abase
      + ((long)((row0 >> 4) + 2 * wave) * nkt) * 512 + lane * 8;
  int quad = lane >> 4, cl = lane & 15;
  int sw8 = ((quad + ((cl >> 1) & 3)) & 3) * 8;   // swizzled read slot
  long fragoff = (long)cl * 32 + sw8;
  long ebase = (long)e * eStride;
  const unsigned short* Bf0 = Bbase + ebase + ((long)((n0 >> 4) + wn * 4)     * nkt) * 512 + fragoff;
  const unsigned short* Bf1 = Bbase + ebase + ((long)((n0 >> 4) + wn * 4 + 1) * nkt) * 512 + fragoff;
  const unsigned short* Bf2 = Bbase + ebase + ((long)((n0 >> 4) + wn * 4 + 2) * nkt) * 512 + fragoff;
  const unsigned short* Bf3 = Bbase + ebase + ((long)((n0 >> 4) + wn * 4 + 3) * nkt) * 512 + fragoff;
  unsigned short* lA0 = lds + wave * 1024 + lane * 8;
  f32x4 acc[4][4];
  f32x4 z = {0.f, 0.f, 0.f, 0.f};
  for (int i = 0; i < 4; i++) for (int j = 0; j < 4; j++) acc[i][j] = z;
  int nk = Kd >> 5;                               // >= 16 always
  // prologue: stage A tiles 0,1; then load B(0)
  GLDS(apk, lA0);              GLDS(apk + sstep, lA0 + 512);
  GLDS(apk + 512, lA0 + 4096); GLDS(apk + sstep + 512, lA0 + 4096 + 512);
  asm volatile("" ::: "memory");
  bf16x8 cb0 = *(const bf16x8*)(Bf0);
  bf16x8 cb1 = *(const bf16x8*)(Bf1);
  bf16x8 cb2 = *(const bf16x8*)(Bf2);
  bf16x8 cb3 = *(const bf16x8*)(Bf3);
  int cur = 0, nxt = 4096, fut = 8192;
  for (int t = 0; t < nk; ++t) {
    __builtin_amdgcn_s_barrier();          // A: ring[fut] free
    if (t + 2 < nk) {
      long k2 = (long)(t + 2) * 512;
      GLDS(apk + k2, lA0 + fut); GLDS(apk + sstep + k2, lA0 + fut + 512);
      asm volatile("s_waitcnt vmcnt(8)" ::: "memory");   // A(t) landed
    } else if (t + 1 < nk) {
      asm volatile("s_waitcnt vmcnt(6)" ::: "memory");
    } else {
      asm volatile("s_waitcnt vmcnt(4)" ::: "memory");
    }
    __builtin_amdgcn_s_barrier();          // B: tile t visible
    asm volatile("" ::: "memory");
    bf16x8 nb0, nb1, nb2, nb3;
    if (t + 1 < nk) {
      long o = (long)(t + 1) * 512;
      nb0 = *(const bf16x8*)(Bf0 + o);
      nb1 = *(const bf16x8*)(Bf1 + o);
      nb2 = *(const bf16x8*)(Bf2 + o);
      nb3 = *(const bf16x8*)(Bf3 + o);
    }
    bf16x8 af[4];
#pragma unroll
    for (int mi = 0; mi < 4; mi++)
      af[mi] = *(const bf16x8*)(lds + cur + (wm * 64 + mi * 16 + cl) * 32 + sw8);
#pragma unroll
    for (int mi = 0; mi < 4; mi++) {
      acc[mi][0] = __builtin_amdgcn_mfma_f32_16x16x32_bf16(af[mi], cb0, acc[mi][0], 0, 0, 0);
      acc[mi][1] = __builtin_amdgcn_mfma_f32_16x16x32_bf16(af[mi], cb1, acc[mi][1], 0, 0, 0);
      acc[mi][2] = __builtin_amdgcn_mfma_f32_16x16x32_bf16(af[mi], cb2, acc[mi][2], 0, 0, 0);
      acc[mi][3] = __builtin_amdgcn_mfma_f32_16x16x32_bf16(af[mi], cb3, acc[mi][3], 0, 0, 0);
    }
    asm volatile("" ::: "memory");
    if (t + 1 < nk) { cb0 = nb0; cb1 = nb1; cb2 = nb2; cb3 = nb3; }
    int tmp = cur; cur = nxt; nxt = fut; fut = tmp;
  }
#pragma unroll
  for (int mi = 0; mi < 4; mi++) {
    int rowb = row0 + wm * 64 + mi * 16 + quad * 4;
#pragma unroll
    for (int r = 0; r < 4; r++) {
      int row = rowb + r;
      if (row >= end) continue;
      if (mode) {
        unsigned short* Y = (unsigned short*)Outv;
        float scale = wslot[row] * 2.5f;
#pragma unroll
        for (int ni = 0; ni < 4; ni++) {
          int col = n0 + wn * 64 + ni * 16 + cl;
          Y[(long)row * HH + col] = f2bf(acc[mi][ni][r] * scale);
        }
      } else {
        float* O = (float*)Outv;
#pragma unroll
        for (int ni = 0; ni < 4; ni++) {
          int col = n0 + wn * 64 + ni * 16 + cl;
          O[(long)row * HH + col] = acc[mi][ni][r];
        }
      }
    }
  }
}

// ---------------- combine: out[t] += sum_k ys[inv[t][k]]  (ys pre-scaled)
__global__ __launch_bounds__(256) void k_combine(const unsigned short* __restrict__ ys,
    const int* __restrict__ inv, float* __restrict__ out)
{
  int idx = blockIdx.x * 256 + threadIdx.x;   // T * 128 threads
  int t = idx >> 7, c0 = (idx & 127) << 3;
  const int* ip = inv + (long)t * KT;
  float* op = out + (long)t * HH + c0;
  float4 o0 = *(float4*)op;
  float4 o1 = *(float4*)(op + 4);
  float a[8] = {o0.x, o0.y, o0.z, o0.w, o1.x, o1.y, o1.z, o1.w};
#pragma unroll
  for (int k = 0; k < KT; k++) {
    us8v v = *(const us8v*)(ys + (long)ip[k] * HH + c0);
#pragma unroll
    for (int j = 0; j < 8; j++) a[j] += __uint_as_float((unsigned)v[j] << 16);
  }
  *(float4*)op = make_float4(a[0], a[1], a[2], a[3]);
  *(float4*)(op + 4) = make_float4(a[4], a[5], a[6], a[7]);
}

extern "C" void kernel_launch(void* const* d_in, const int* in_sizes, int n_in,
                              void* d_out, int out_size, void* d_ws, size_t ws_size,
                              hipStream_t stream)
{
  const float* x   = (const float*)d_in[0];
  const float* gw  = (const float*)d_in[1];
  const float* eb  = (const float*)d_in[2];
  const float* w1  = (const float*)d_in[3];
  const float* w2  = (const float*)d_in[4];
  const float* sgu = (const float*)d_in[5];
  const float* sd  = (const float*)d_in[6];
  float* out = (float*)d_out;
  char* ws = (char*)d_ws;
  size_t off = 0;
  auto alloc = [&](size_t b) { void* p = ws + off; off += (b + 255) & ~(size_t)255; return p; };
  unsigned short* w1t  = (unsigned short*)alloc((size_t)EE * 2 * II * HH * 2);  // [E] packed [2I][H]
  unsigned short* w2t  = (unsigned short*)alloc((size_t)EE * HH * II * 2);      // [E] packed [H][I]
  unsigned short* sgut = (unsigned short*)alloc((size_t)2 * ISZ * HH * 2);      // packed [2IS][H]
  unsigned short* sdt  = (unsigned short*)alloc((size_t)HH * ISZ * 2);          // packed [H][IS]
  unsigned short* xb   = (unsigned short*)alloc((size_t)TT * HH * 2);           // x bf16 row-major
  unsigned short* hsb  = (unsigned short*)alloc((size_t)TT * ISZ * 2);          // shared h (packed)
  unsigned short* hb   = (unsigned short*)alloc((size_t)TKAP * II * 2);         // routed h (packed)
  unsigned short* ys   = (unsigned short*)alloc((size_t)TKAP * HH * 2);         // routed down out (row-major)
  int*   tids   = (int*)alloc((size_t)TKA * 4);
  float* tw     = (float*)alloc((size_t)TKA * 4);
  int*   counts = (int*)alloc(256);
  int*   offs   = (int*)alloc(512);
  int*   cursor = (int*)alloc(256);
  int*   tile_e = (int*)alloc(MAXT * 4);
  int*   tile_r = (int*)alloc(MAXT * 4);
  int*   perm   = (int*)alloc((size_t)TKAP * 4);
  float* wslot  = (float*)alloc((size_t)TKAP * 4);
  int*   inv    = (int*)alloc((size_t)TKA * 4);

  hipMemsetAsync(counts, 0, 256, stream);
  dim3 b256(256);
  // weight transpose+convert+pack (bf16 [N][K] in MFMA-subtile order)
  k_transpose<<<dim3(HH / 64, (2 * II) / 64, EE), b256, 0, stream>>>(w1, w1t, HH, 2 * II);
  k_transpose<<<dim3(II / 64, HH / 64, EE), b256, 0, stream>>>(w2, w2t, II, HH);
  k_transpose<<<dim3(HH / 64, (2 * ISZ) / 64, 1), b256, 0, stream>>>(sgu, sgut, HH, 2 * ISZ);
  k_transpose<<<dim3(ISZ / 64, HH / 64, 1), b256, 0, stream>>>(sd, sdt, ISZ, HH);
  k_cvt<<<dim3((TT * HH) / 1024), b256, 0, stream>>>(x, xb);
  // routing
  k_router<<<dim3(TT), b256, 0, stream>>>(x, gw, eb, tids, tw, counts);
  k_offsets<<<dim3(1), dim3(64), 0, stream>>>(counts, offs, cursor, tile_e, tile_r, perm, wslot);
  k_scatter<<<dim3(TKA / 256), b256, 0, stream>>>(tids, tw, cursor, perm, wslot, inv);
  // routed path: GEMM1 (gathered A via perm) -> ys (scaled bf16)
  k_gemm_gu<<<dim3(MAXT, II / 64), b256, 0, stream>>>(xb, perm, w1t, (long)2 * II * HH, HH, II,
                                                      hb, tile_e, tile_r, offs, TKAP);
  k_gemm_down<<<dim3(MAXT, HH / 128), b256, 0, stream>>>(hb, w2t, (long)HH * II, II, (void*)ys,
                                                         wslot, tile_e, tile_r, offs, TKAP, 1);
  // shared path -> out (fp32)
  k_gemm_gu<<<dim3(TT / 128, ISZ / 64), b256, 0, stream>>>(xb, nullptr, sgut, 0, HH, ISZ,
                                                           hsb, nullptr, nullptr, nullptr, TT);
  k_gemm_down<<<dim3(TT / 128, HH / 128), b256, 0, stream>>>(hsb, sdt, 0, ISZ, (void*)out,
                                                             nullptr, nullptr, nullptr, nullptr, TT, 0);
  // combine: out += gathered ys
  k_combine<<<dim3(TT * 128 / 256), b256, 0, stream>>>(ys, inv, out);
}

// Round 6
// 856.480 us; speedup vs baseline: 1.0492x; 1.0492x over previous
//
#include <hip/hip_runtime.h>
#include <cstdint>
#include <cstddef>

// Problem constants (match reference config)
#define TT   4096     // tokens
#define HH   1024     // hidden
#define II   512      // moe intermediate
#define EE   64       // experts
#define KT   8        // top-k
#define ISZ  1024     // shared intermediate (I*NSH)
#define TKA  32768    // T*K assignments
#define TKAP (TKA + 2048)  // padded slots (16-align per expert + last-tile overhang)
#define MAXT 320      // max M-tiles: sum ceil(n_e/128) <= 256+64

typedef __bf16 bf16x8 __attribute__((ext_vector_type(8)));
typedef float  f32x4  __attribute__((ext_vector_type(4)));
typedef unsigned short us8v __attribute__((ext_vector_type(8)));

__device__ __forceinline__ unsigned short f2bf(float f) {
  unsigned u = __float_as_uint(f);
  u += 0x7fffu + ((u >> 16) & 1u);   // RNE (finite inputs only)
  return (unsigned short)(u >> 16);
}

// async global->LDS, 16B/lane; LDS dest is wave-uniform base + lane*16
#define GLDS(gp, lp) __builtin_amdgcn_global_load_lds( \
    (const __attribute__((address_space(1))) void*)(gp), \
    (__attribute__((address_space(3))) void*)(lp), 16, 0, 0)

// PACKED weight layout: logical [N][K] bf16 stored as subtiles of 16n x 32k
// (1024 B contiguous). Element (n&15, k) sits at (n&15)*32 + s*8 + (k&7),
// s = ((k>>3)&3 + ((n>>1)&3)) & 3 (bank swizzle baked in). A wave's GLDS of
// one subtile (lane*16B) is a single coalesced 1 KiB transaction; fragment
// reads use the sw8 slot formula. B staging is via LDS (R4 form) -- the R5
// direct-to-VGPR variant measured SLOWER (L2 pipe 56 B/cyc/CU + duplicated
// loads across waves vs LDS 85+ B/cyc/CU shared) -- keep LDS staging.

// ---------------- transpose tile helper: 64x64 fp32 -> packed bf16
__device__ __forceinline__ void transpose_tile(const float* __restrict__ ip,
                                               unsigned short* __restrict__ op,
                                               int R, int C, int r0, int c0,
                                               float (*tile)[65]) {
  int tc = threadIdx.x & 63, tr = threadIdx.x >> 6;
#pragma unroll
  for (int rr = 0; rr < 64; rr += 4)
    tile[tr + rr][tc] = ip[(long)(r0 + tr + rr) * C + (c0 + tc)];
  __syncthreads();
  int kt = R >> 5;   // k-tiles per n-group
#pragma unroll
  for (int p = 0; p < 2; p++) {
    int sid = p * 256 + threadIdx.x;     // 512 slots: 64 n x 8 kq
    int nl = sid >> 3, kq = sid & 7;
    int n = c0 + nl;
    int kg = r0 + kq * 8;
    int s = ((kq & 3) + ((n >> 1) & 3)) & 3;
    long off = ((long)(n >> 4) * kt + (kg >> 5)) * 512 + (n & 15) * 32 + s * 8;
    us8v v;
#pragma unroll
    for (int j = 0; j < 8; j++) v[j] = f2bf(tile[kq * 8 + j][nl]);
    *(us8v*)(op + off) = v;
  }
}

// ---------------- fused prep: 4 weight transposes + x cvt + counts zero.
// Segmented 1-D grid (uniform per-block branch -> __syncthreads is safe):
//  [0,16384)           w1  (e = b>>8, r = (b>>4)&15, c = b&15)   R=1024 C=1024
//  [16384,24576)       w2  (e = b>>7, r = (b>>4)&7,  c = b&15)   R=512  C=1024
//  [24576,25088)       sgu (r = b&15, c = b>>4)                  R=1024 C=2048
//  [25088,25344)       sd  (r = b&15, c = b>>4)                  R=1024 C=1024
//  [25344,29440)       x cvt (1024 floats/block)
#define PREP_NB 29440
__global__ __launch_bounds__(256) void k_prep(
    const float* __restrict__ w1, const float* __restrict__ w2,
    const float* __restrict__ sgu, const float* __restrict__ sd,
    const float* __restrict__ x,
    unsigned short* __restrict__ w1t, unsigned short* __restrict__ w2t,
    unsigned short* __restrict__ sgut, unsigned short* __restrict__ sdt,
    unsigned short* __restrict__ xb, int* __restrict__ counts)
{
  __shared__ float tile[64][65];
  int b = blockIdx.x;
  if (b < 16384) {
    int e = b >> 8, r = (b >> 4) & 15, c = b & 15;
    transpose_tile(w1 + (long)e * HH * (2 * II), w1t + (long)e * HH * (2 * II),
                   HH, 2 * II, r * 64, c * 64, tile);
  } else if (b < 24576) {
    int b2 = b - 16384;
    int e = b2 >> 7, r = (b2 >> 4) & 7, c = b2 & 15;
    transpose_tile(w2 + (long)e * II * HH, w2t + (long)e * II * HH,
                   II, HH, r * 64, c * 64, tile);
  } else if (b < 25088) {
    int b3 = b - 24576;
    int r = b3 & 15, c = b3 >> 4;                 // c < 32
    transpose_tile(sgu, sgut, HH, 2 * ISZ, r * 64, c * 64, tile);
  } else if (b < 25344) {
    int b4 = b - 25088;
    int r = b4 & 15, c = b4 >> 4;                 // c < 16
    transpose_tile(sd, sdt, ISZ, HH, r * 64, c * 64, tile);
  } else {
    int b5 = b - 25344;
    if (b5 == 0 && threadIdx.x < 64) counts[threadIdx.x] = 0;
    int i = b5 * 256 + threadIdx.x;
    float4 v = ((const float4*)x)[i];
    ushort4 o;
    o.x = f2bf(v.x); o.y = f2bf(v.y); o.z = f2bf(v.z); o.w = f2bf(v.w);
    ((ushort4*)xb)[i] = o;
  }
}

// ---------------- router: fp64-accurate logits -> sigmoid -> wave-parallel
// grouped top-k (lane = expert, all state in registers, shuffles only).
__global__ __launch_bounds__(256) void k_router(const float* __restrict__ x,
    const float* __restrict__ gw, const float* __restrict__ eb,
    int* __restrict__ topk_ids, float* __restrict__ topk_w, int* __restrict__ counts)
{
  __shared__ float xrow[HH];
  __shared__ float sc[EE];
  int t = blockIdx.x;
  int tid = threadIdx.x;
  for (int i = tid; i < HH; i += 256) xrow[i] = x[(long)t * HH + i];
  __syncthreads();
  int e = tid >> 2, q = tid & 3;          // 4 threads per expert
  const float* w = gw + (long)e * HH;
  double acc = 0.0, acc2 = 0.0;           // 2 chains to halve dep latency
  for (int i = q * 8; i < HH; i += 32) {
    float4 wa = *(const float4*)(w + i);
    float4 wb = *(const float4*)(w + i + 4);
    acc  += (double)wa.x * (double)xrow[i]
          + (double)wa.y * (double)xrow[i + 1]
          + (double)wa.z * (double)xrow[i + 2]
          + (double)wa.w * (double)xrow[i + 3];
    acc2 += (double)wb.x * (double)xrow[i + 4]
          + (double)wb.y * (double)xrow[i + 5]
          + (double)wb.z * (double)xrow[i + 6]
          + (double)wb.w * (double)xrow[i + 7];
  }
  acc += acc2;
  acc += __shfl_down(acc, 2);
  acc += __shfl_down(acc, 1);
  if (q == 0) sc[e] = (float)(1.0 / (1.0 + exp(-acc)));
  __syncthreads();
  if (tid < 64) {                          // wave 0, lane = expert
    int lane = tid;
    float s = sc[lane];
    float sfc = s + eb[lane];
    // --- top-2 within each group of 8 lanes (butterfly top-2 merge)
    float m1 = sfc, m2 = -1e30f;
#pragma unroll
    for (int d = 1; d < 8; d <<= 1) {
      float o1 = __shfl_xor(m1, d);
      float o2 = __shfl_xor(m2, d);
      float hi = fmaxf(m1, o1);
      float lo = fminf(m1, o1);
      m2 = fmaxf(lo, fmaxf(m2, o2));
      m1 = hi;
    }
    float gs = m1 + m2;                    // group score (uniform within group)
    int g = lane >> 3;
    // --- rank my group among 8 (ties -> lowest group idx), select top-4
    int grank = 0;
#pragma unroll
    for (int j = 0; j < 8; j++) {
      float gj = __shfl(gs, j * 8);
      if (gj > gs || (gj == gs && j < g)) grank++;
    }
    bool gsel = grank < 4;
    float mv = gsel ? sfc : 0.0f;          // masked_fill(~mask, 0.0) as in ref
    // --- rank among all 64 (ties -> lowest lane), select top-8
    int rank = 0;
    for (int j = 0; j < 64; j++) {
      float vj = __shfl(mv, j);
      if (vj > mv || (vj == mv && j < lane)) rank++;
    }
    bool sel = rank < KT;
    float ssum = sel ? s : 0.0f;           // renorm sum of RAW scores
#pragma unroll
    for (int d = 1; d < 64; d <<= 1) ssum += __shfl_xor(ssum, d);
    unsigned long long bal = __ballot(sel);
    if (sel) {
      int pos = __popcll(bal & ((1ull << lane) - 1ull));
      topk_ids[(long)t * KT + pos] = lane;
      topk_w[(long)t * KT + pos] = s / ssum;
      atomicAdd(&counts[lane], 1);
    }
  }
}

// ---------------- offsets (16-aligned per expert) + static tile table
// + zero-init of padding slots in perm/wslot (they get staged but masked).
__global__ void k_offsets(const int* __restrict__ counts, int* __restrict__ offsets,
                          int* __restrict__ cursor, int* __restrict__ tile_e,
                          int* __restrict__ tile_r0, int* __restrict__ perm,
                          float* __restrict__ wslot)
{
  int lane = threadIdx.x;                  // 64 threads = 1 wave
  int c = counts[lane];
  int ca = (c + 15) & ~15;                 // 16-aligned (packed-subtile alignment)
  int xs = ca;                             // inclusive prefix sum of padded counts
#pragma unroll
  for (int d = 1; d < 64; d <<= 1) { int y = __shfl_up(xs, d); if (lane >= d) xs += y; }
  int off = xs - ca;                       // exclusive (16-aligned)
  offsets[lane] = off;
  cursor[lane] = off;
  if (lane == 63) offsets[EE] = xs;
  int nt = (c + 127) >> 7;                 // M-tiles for this expert
  int tp = nt;                             // inclusive prefix sum of tiles
#pragma unroll
  for (int d = 1; d < 64; d <<= 1) { int y = __shfl_up(tp, d); if (lane >= d) tp += y; }
  int tbase = tp - nt;
  for (int i = 0; i < nt; i++) { tile_e[tbase + i] = lane; tile_r0[tbase + i] = off + i * 128; }
  int total = __shfl(tp, 63);
  for (int i = total + lane; i < MAXT; i += 64) tile_e[i] = -1;
  // zero padding slots [off+c, off+ca) so staged perm/wslot are defined
  for (int i = off + c; i < off + ca; i++) { perm[i] = 0; wslot[i] = 0.f; }
  // last expert's tile overhang [paddedTotal, lastTileEnd)
  int ptotal = __shfl(xs, 63);
  int lastEnd = __shfl(off + nt * 128, 63);
  for (int i = ptotal + lane; i < lastEnd; i += 64) { perm[i] = 0; wslot[i] = 0.f; }
}

// ---------------- scatter assignments into expert-sorted slot order
__global__ __launch_bounds__(256) void k_scatter(const int* __restrict__ ids,
    const float* __restrict__ tw, int* __restrict__ cursor,
    int* __restrict__ perm, float* __restrict__ wslot, int* __restrict__ inv)
{
  int a = blockIdx.x * 256 + threadIdx.x;
  int e = ids[a];
  int pos = atomicAdd(&cursor[e], 1);
  perm[pos] = a >> 3;     // token index
  wslot[pos] = tw[a];
  inv[a] = pos;           // token t, k-th pick -> slot
}

// ---------------- GEMM1 (gate_up) + fused silu*mul. Twin accumulators:
// block: 128 rows x 64 gate cols + 64 up cols. 4 waves (2x2), 16x16x32 bf16 MFMA.
// 3-deep LDS ring, counted vmcnt (T4), XCD-chunked order (T1), packed-B
// staging (coalesced 1 KiB GLDS/wave). Epilogue writes Hout PACKED.  [R4 form]
__global__ __launch_bounds__(256) void k_gemm_gu(
    const unsigned short* __restrict__ Abase, const int* __restrict__ perm,
    const unsigned short* __restrict__ Bbase, long eStride, int Kd, int upOff,
    unsigned short* __restrict__ Hout,
    const int* __restrict__ tile_e, const int* __restrict__ tile_r0,
    const int* __restrict__ eoff, int rowsTotal)
{
  __shared__ __align__(16) unsigned short lds[24576];  // 3 x (A 4096 | Bg 2048 | Bu 2048)
  // XCD swizzle: D%8 = XCD; each XCD owns gridDim.x/8 contiguous M-tiles, N-fastest
  int D = blockIdx.y * gridDim.x + blockIdx.x;
  int cx = D & 7, jj = D >> 3;
  int chunk = gridDim.x >> 3;
  int mt = cx * chunk + jj / gridDim.y;
  int ny = jj - (jj / gridDim.y) * gridDim.y;
  int e = 0, row0, end;
  if (tile_e) {
    e = tile_e[mt];
    if (e < 0) return;
    row0 = tile_r0[mt];
    end = eoff[e + 1];
  } else { row0 = mt * 128; end = rowsTotal; }
  int n0 = ny * 64;
  int tid = threadIdx.x, lane = tid & 63, wave = tid >> 6;
  int wm = wave >> 1, wn = wave & 1;
  int lr = lane >> 2;
  int lkq = ((((lane & 3) - ((lane >> 3) & 3)) & 3)) * 8;  // swizzled k-chunk (A path)
  int r0a = row0 + wave * 32 + lr;
  int r1a = r0a + 16;
  int t0 = r0a < rowsTotal ? r0a : rowsTotal - 1;
  int t1 = r1a < rowsTotal ? r1a : rowsTotal - 1;
  if (perm) { t0 = perm[t0]; t1 = perm[t1]; }
  const unsigned short* ap0 = Abase + (long)t0 * Kd + lkq;
  const unsigned short* ap1 = Abase + (long)t1 * Kd + lkq;
  int nkt = Kd >> 5;                       // packed k-tiles per n-group
  const unsigned short* bgp = Bbase + (long)e * eStride
      + ((long)((n0 >> 4) + wave) * nkt) * 512 + lane * 8;
  const unsigned short* bup = Bbase + (long)e * eStride
      + ((long)(((upOff + n0) >> 4) + wave) * nkt) * 512 + lane * 8;
  unsigned short* lA0 = lds + wave * 1024 + lane * 8;          // rows wave*32..  (+512 = +16 rows)
  unsigned short* lBg = lds + 4096 + wave * 512 + lane * 8;    // subtile wave (rows 16w..)
  unsigned short* lBu = lds + 6144 + wave * 512 + lane * 8;
  f32x4 acc[4][4];
  f32x4 z = {0.f, 0.f, 0.f, 0.f};
  for (int i = 0; i < 4; i++) for (int j = 0; j < 4; j++) acc[i][j] = z;
  int quad = lane >> 4, cl = lane & 15;
  int sw8 = ((quad + ((cl >> 1) & 3)) & 3) * 8;   // swizzled read slot
  int nk = Kd >> 5;                               // >= 16 always
  // prologue: stage tiles 0,1 into ring slots 0,1 (8 loads in flight)
  GLDS(ap0, lA0);             GLDS(ap1, lA0 + 512);
  GLDS(bgp, lBg);             GLDS(bup, lBu);
  GLDS(ap0 + 32, lA0 + 8192); GLDS(ap1 + 32, lA0 + 8192 + 512);
  GLDS(bgp + 512, lBg + 8192); GLDS(bup + 512, lBu + 8192);
  int cur = 0, nxt = 8192, fut = 16384;
  for (int t = 0; t < nk; ++t) {
    __builtin_amdgcn_s_barrier();          // A: all waves done reading ring[fut]
    if (t + 2 < nk) {
      int k2 = (t + 2) << 5;
      GLDS(ap0 + k2, lA0 + fut); GLDS(ap1 + k2, lA0 + fut + 512);
      GLDS(bgp + (long)(t + 2) * 512, lBg + fut);
      GLDS(bup + (long)(t + 2) * 512, lBu + fut);
      asm volatile("s_waitcnt vmcnt(8)" ::: "memory");   // tile t landed (FIFO)
    } else if (t + 1 < nk) {
      asm volatile("s_waitcnt vmcnt(4)" ::: "memory");
    } else {
      asm volatile("s_waitcnt vmcnt(0)" ::: "memory");
    }
    __builtin_amdgcn_s_barrier();          // B: tile t visible to all waves
    asm volatile("" ::: "memory");         // pin ds_reads below barrier B
    bf16x8 af[4], bgf[2], buf2[2];
#pragma unroll
    for (int mi = 0; mi < 4; mi++)
      af[mi] = *(const bf16x8*)(lds + cur + (wm * 64 + mi * 16 + cl) * 32 + sw8);
#pragma unroll
    for (int ni = 0; ni < 2; ni++) {
      bgf[ni]  = *(const bf16x8*)(lds + cur + 4096 + (wn * 32 + ni * 16 + cl) * 32 + sw8);
      buf2[ni] = *(const bf16x8*)(lds + cur + 6144 + (wn * 32 + ni * 16 + cl) * 32 + sw8);
    }
#pragma unroll
    for (int mi = 0; mi < 4; mi++) {
#pragma unroll
      for (int ni = 0; ni < 2; ni++) {
        acc[mi][ni]     = __builtin_amdgcn_mfma_f32_16x16x32_bf16(af[mi], bgf[ni],  acc[mi][ni],     0, 0, 0);
        acc[mi][ni + 2] = __builtin_amdgcn_mfma_f32_16x16x32_bf16(af[mi], buf2[ni], acc[mi][ni + 2], 0, 0, 0);
      }
    }
    asm volatile("" ::: "memory");         // pin ds_reads above next barrier A
    int tmp = cur; cur = nxt; nxt = fut; fut = tmp;
  }
  int ntO = upOff >> 5;                    // packed k-tiles of output (K = upOff)
#pragma unroll
  for (int mi = 0; mi < 4; mi++) {
#pragma unroll
    for (int j = 0; j < 2; j++) {
#pragma unroll
      for (int r = 0; r < 4; r++) {
        int row = row0 + wm * 64 + mi * 16 + quad * 4 + r;
        if (row < end) {
          float g = acc[mi][j][r], u = acc[mi][j + 2][r];
          float hv = g * (1.f / (1.f + __expf(-g))) * u;   // silu(g)*u
          int col = n0 + wn * 32 + j * 16 + cl;
          int sl = (((col >> 3) & 3) + ((row >> 1) & 3)) & 3;
          long offp = ((long)(row >> 4) * ntO + (col >> 5)) * 512
                    + (row & 15) * 32 + sl * 8 + (col & 7);
          Hout[offp] = f2bf(hv);
        }
      }
    }
  }
}

// ---------------- GEMM2 (down). 128x128 tile. 3-deep ring + counted vmcnt +
// XCD chunks. A (packed Hout) and B (packed weights) both coalesced GLDS. [R4 form]
// mode 0: plain fp32 store to Out (shared path)
// mode 1: scaled bf16 store to Out (routed ys; scale = wslot*2.5)
__global__ __launch_bounds__(256) void k_gemm_down(
    const unsigned short* __restrict__ Abase,
    const unsigned short* __restrict__ Bbase, long eStride, int Kd,
    void* __restrict__ Outv, const float* __restrict__ wslot,
    const int* __restrict__ tile_e, const int* __restrict__ tile_r0,
    const int* __restrict__ eoff, int rowsTotal, int mode)
{
  __shared__ __align__(16) unsigned short lds[24576];  // 3 x (A 4096 | B 4096)
  int D = blockIdx.y * gridDim.x + blockIdx.x;
  int cx = D & 7, jj = D >> 3;
  int chunk = gridDim.x >> 3;
  int mt = cx * chunk + jj / gridDim.y;
  int ny = jj - (jj / gridDim.y) * gridDim.y;
  int e = 0, row0, end;
  if (tile_e) {
    e = tile_e[mt];
    if (e < 0) return;
    row0 = tile_r0[mt];                    // 16-aligned (padded offsets)
    end = eoff[e + 1];
  } else { row0 = mt * 128; end = rowsTotal; }
  int n0 = ny * 128;
  int tid = threadIdx.x, lane = tid & 63, wave = tid >> 6;
  int wm = wave >> 1, wn = wave & 1;
  int nkt = Kd >> 5;
  long sstep = (long)nkt * 512;            // next n-group subtile stride
  const unsigned short* apk = Abase
      + ((long)((row0 >> 4) + 2 * wave) * nkt) * 512 + lane * 8;
  const unsigned short* bpk = Bbase + (long)e * eStride
      + ((long)((n0 >> 4) + 2 * wave) * nkt) * 512 + lane * 8;
  unsigned short* lA0 = lds + wave * 1024 + lane * 8;
  unsigned short* lB0 = lds + 4096 + wave * 1024 + lane * 8;
  f32x4 acc[4][4];
  f32x4 z = {0.f, 0.f, 0.f, 0.f};
  for (int i = 0; i < 4; i++) for (int j = 0; j < 4; j++) acc[i][j] = z;
  int quad = lane >> 4, cl = lane & 15;
  int sw8 = ((quad + ((cl >> 1) & 3)) & 3) * 8;   // swizzled read slot
  int nk = Kd >> 5;                               // >= 16 always
  // prologue: stage tiles 0,1
  GLDS(apk, lA0);              GLDS(apk + sstep, lA0 + 512);
  GLDS(bpk, lB0);              GLDS(bpk + sstep, lB0 + 512);
  GLDS(apk + 512, lA0 + 8192); GLDS(apk + sstep + 512, lA0 + 8192 + 512);
  GLDS(bpk + 512, lB0 + 8192); GLDS(bpk + sstep + 512, lB0 + 8192 + 512);
  int cur = 0, nxt = 8192, fut = 16384;
  for (int t = 0; t < nk; ++t) {
    __builtin_amdgcn_s_barrier();          // A: ring[fut] free
    if (t + 2 < nk) {
      long k2 = (long)(t + 2) * 512;
      GLDS(apk + k2, lA0 + fut); GLDS(apk + sstep + k2, lA0 + fut + 512);
      GLDS(bpk + k2, lB0 + fut); GLDS(bpk + sstep + k2, lB0 + fut + 512);
      asm volatile("s_waitcnt vmcnt(8)" ::: "memory");   // tile t landed
    } else if (t + 1 < nk) {
      asm volatile("s_waitcnt vmcnt(4)" ::: "memory");
    } else {
      asm volatile("s_waitcnt vmcnt(0)" ::: "memory");
    }
    __builtin_amdgcn_s_barrier();          // B: tile t visible
    asm volatile("" ::: "memory");
    bf16x8 af[4], bfr[4];
#pragma unroll
    for (int mi = 0; mi < 4; mi++)
      af[mi] = *(const bf16x8*)(lds + cur + (wm * 64 + mi * 16 + cl) * 32 + sw8);
#pragma unroll
    for (int ni = 0; ni < 4; ni++)
      bfr[ni] = *(const bf16x8*)(lds + cur + 4096 + (wn * 64 + ni * 16 + cl) * 32 + sw8);
#pragma unroll
    for (int mi = 0; mi < 4; mi++)
#pragma unroll
      for (int ni = 0; ni < 4; ni++)
        acc[mi][ni] = __builtin_amdgcn_mfma_f32_16x16x32_bf16(af[mi], bfr[ni], acc[mi][ni], 0, 0, 0);
    asm volatile("" ::: "memory");
    int tmp = cur; cur = nxt; nxt = fut; fut = tmp;
  }
#pragma unroll
  for (int mi = 0; mi < 4; mi++) {
    int rowb = row0 + wm * 64 + mi * 16 + quad * 4;
#pragma unroll
    for (int r = 0; r < 4; r++) {
      int row = rowb + r;
      if (row >= end) continue;
      if (mode) {
        unsigned short* Y = (unsigned short*)Outv;
        float scale = wslot[row] * 2.5f;
#pragma unroll
        for (int ni = 0; ni < 4; ni++) {
          int col = n0 + wn * 64 + ni * 16 + cl;
          Y[(long)row * HH + col] = f2bf(acc[mi][ni][r] * scale);
        }
      } else {
        float* O = (float*)Outv;
#pragma unroll
        for (int ni = 0; ni < 4; ni++) {
          int col = n0 + wn * 64 + ni * 16 + cl;
          O[(long)row * HH + col] = acc[mi][ni][r];
        }
      }
    }
  }
}

// ---------------- combine: out[t] += sum_k ys[inv[t][k]]  (ys pre-scaled)
__global__ __launch_bounds__(256) void k_combine(const unsigned short* __restrict__ ys,
    const int* __restrict__ inv, float* __restrict__ out)
{
  int idx = blockIdx.x * 256 + threadIdx.x;   // T * 128 threads
  int t = idx >> 7, c0 = (idx & 127) << 3;
  const int* ip = inv + (long)t * KT;
  float* op = out + (long)t * HH + c0;
  float4 o0 = *(float4*)op;
  float4 o1 = *(float4*)(op + 4);
  float a[8] = {o0.x, o0.y, o0.z, o0.w, o1.x, o1.y, o1.z, o1.w};
#pragma unroll
  for (int k = 0; k < KT; k++) {
    us8v v = *(const us8v*)(ys + (long)ip[k] * HH + c0);
#pragma unroll
    for (int j = 0; j < 8; j++) a[j] += __uint_as_float((unsigned)v[j] << 16);
  }
  *(float4*)op = make_float4(a[0], a[1], a[2], a[3]);
  *(float4*)(op + 4) = make_float4(a[4], a[5], a[6], a[7]);
}

extern "C" void kernel_launch(void* const* d_in, const int* in_sizes, int n_in,
                              void* d_out, int out_size, void* d_ws, size_t ws_size,
                              hipStream_t stream)
{
  const float* x   = (const float*)d_in[0];
  const float* gw  = (const float*)d_in[1];
  const float* eb  = (const float*)d_in[2];
  const float* w1  = (const float*)d_in[3];
  const float* w2  = (const float*)d_in[4];
  const float* sgu = (const float*)d_in[5];
  const float* sd  = (const float*)d_in[6];
  float* out = (float*)d_out;
  char* ws = (char*)d_ws;
  size_t off = 0;
  auto alloc = [&](size_t b) { void* p = ws + off; off += (b + 255) & ~(size_t)255; return p; };
  unsigned short* w1t  = (unsigned short*)alloc((size_t)EE * 2 * II * HH * 2);  // [E] packed [2I][H]
  unsigned short* w2t  = (unsigned short*)alloc((size_t)EE * HH * II * 2);      // [E] packed [H][I]
  unsigned short* sgut = (unsigned short*)alloc((size_t)2 * ISZ * HH * 2);      // packed [2IS][H]
  unsigned short* sdt  = (unsigned short*)alloc((size_t)HH * ISZ * 2);          // packed [H][IS]
  unsigned short* xb   = (unsigned short*)alloc((size_t)TT * HH * 2);           // x bf16 row-major
  unsigned short* hsb  = (unsigned short*)alloc((size_t)TT * ISZ * 2);          // shared h (packed)
  unsigned short* hb   = (unsigned short*)alloc((size_t)TKAP * II * 2);         // routed h (packed)
  unsigned short* ys   = (unsigned short*)alloc((size_t)TKAP * HH * 2);         // routed down out (row-major)
  int*   tids   = (int*)alloc((size_t)TKA * 4);
  float* tw     = (float*)alloc((size_t)TKA * 4);
  int*   counts = (int*)alloc(256);
  int*   offs   = (int*)alloc(512);
  int*   cursor = (int*)alloc(256);
  int*   tile_e = (int*)alloc(MAXT * 4);
  int*   tile_r = (int*)alloc(MAXT * 4);
  int*   perm   = (int*)alloc((size_t)TKAP * 4);
  float* wslot  = (float*)alloc((size_t)TKAP * 4);
  int*   inv    = (int*)alloc((size_t)TKA * 4);

  dim3 b256(256);
  // fused prep: all weight transposes+pack, x cvt, counts zero (1 launch)
  k_prep<<<dim3(PREP_NB), b256, 0, stream>>>(w1, w2, sgu, sd, x,
                                             w1t, w2t, sgut, sdt, xb, counts);
  // routing
  k_router<<<dim3(TT), b256, 0, stream>>>(x, gw, eb, tids, tw, counts);
  k_offsets<<<dim3(1), dim3(64), 0, stream>>>(counts, offs, cursor, tile_e, tile_r, perm, wslot);
  k_scatter<<<dim3(TKA / 256), b256, 0, stream>>>(tids, tw, cursor, perm, wslot, inv);
  // routed path: GEMM1 (gathered A via perm) -> ys (scaled bf16)
  k_gemm_gu<<<dim3(MAXT, II / 64), b256, 0, stream>>>(xb, perm, w1t, (long)2 * II * HH, HH, II,
                                                      hb, tile_e, tile_r, offs, TKAP);
  k_gemm_down<<<dim3(MAXT, HH / 128), b256, 0, stream>>>(hb, w2t, (long)HH * II, II, (void*)ys,
                                                         wslot, tile_e, tile_r, offs, TKAP, 1);
  // shared path -> out (fp32)
  k_gemm_gu<<<dim3(TT / 128, ISZ / 64), b256, 0, stream>>>(xb, nullptr, sgut, 0, HH, ISZ,
                                                           hsb, nullptr, nullptr, nullptr, TT);
  k_gemm_down<<<dim3(TT / 128, HH / 128), b256, 0, stream>>>(hsb, sdt, 0, ISZ, (void*)out,
                                                             nullptr, nullptr, nullptr, nullptr, TT, 0);
  // combine: out += gathered ys
  k_combine<<<dim3(TT * 128 / 256), b256, 0, stream>>>(ys, inv, out);
}